// Round 1
// baseline (48.060 us; speedup 1.0000x reference)
//
#include <hip/hip_runtime.h>

#define NUM_ENT 14541
#define NUM_REL 474
#define DIM     400
#define D4      100   // DIM/4
#define B       32
#define NCAND   14505

#define NT      32    // candidates per block
#define STRIDE  408   // padded LDS row stride (floats); 408/4 % 32 = 6 -> 16 distinct bank quads
#define THREADS 256

// ---------------- prep: q = ent[head] + relc[rel]; o = relo[rel]; base = one + 0.98*sum(o) ---
__global__ void prep_kernel(const float* __restrict__ ent,
                            const float* __restrict__ relc,
                            const float* __restrict__ relo,
                            const float* __restrict__ onev,
                            const int*   __restrict__ pairs,
                            float* __restrict__ qg,
                            float* __restrict__ og,
                            float* __restrict__ baseg) {
    const int b    = blockIdx.x;
    const int lane = threadIdx.x;            // 64 threads, 1 wave
    const int h = pairs[b * 2 + 0];
    const int r = pairs[b * 2 + 1];
    const float4* h4  = (const float4*)(ent  + (size_t)h * DIM);
    const float4* rc4 = (const float4*)(relc + (size_t)r * DIM);
    const float4* ro4 = (const float4*)(relo + (size_t)r * DIM);
    float4* q4 = (float4*)(qg + (size_t)b * DIM);
    float4* o4 = (float4*)(og + (size_t)b * DIM);
    float so = 0.f;
    for (int i = lane; i < D4; i += 64) {
        float4 hv = h4[i], cv = rc4[i], ov = ro4[i];
        float4 qv = make_float4(hv.x + cv.x, hv.y + cv.y, hv.z + cv.z, hv.w + cv.w);
        q4[i] = qv;
        o4[i] = ov;
        so += ov.x + ov.y + ov.z + ov.w;
    }
    for (int off = 32; off; off >>= 1) so += __shfl_down(so, off);
    if (lane == 0) baseg[b] = onev[0] + 0.98f * so;
}

// ---------------- main: out[b][n] = base[b] - 0.98*sum(max(|c-q|,o)) - 0.02*sum(|c-q|) ------
template <bool USE_WS>
__global__ __launch_bounds__(THREADS)
void box_score_kernel(const float* __restrict__ ent,
                      const float* __restrict__ relc,
                      const float* __restrict__ relo,
                      const float* __restrict__ onev,
                      const int*   __restrict__ pairs,
                      const int*   __restrict__ cidx,
                      const float* __restrict__ qg,
                      const float* __restrict__ og,
                      const float* __restrict__ baseg,
                      float* __restrict__ out) {
    __shared__ float cs[NT * STRIDE];
    const int tid    = threadIdx.x;
    const int n_base = blockIdx.x * NT;

    // stage NT gathered candidate rows into LDS (padded stride, float4 loads)
    for (int s = tid; s < NT * D4; s += THREADS) {
        int row = s / D4;
        int col = s - row * D4;
        int n   = n_base + row;
        if (n >= NCAND) n = NCAND - 1;          // clamp: harmless duplicate row
        int ci = cidx[n];
        float4 v = ((const float4*)(ent + (size_t)ci * DIM))[col];
        *(float4*)&cs[row * STRIDE + col * 4] = v;
    }
    __syncthreads();

    const int jn = tid & 15;     // candidate group: n0 = jn, n1 = jn+16
    const int bg = tid >> 4;     // batch group:     b0 = bg, b1 = bg+16
    const int b0 = bg, b1 = bg + 16;

    const float4* c0p = (const float4*)&cs[jn * STRIDE];
    const float4* c1p = (const float4*)&cs[(jn + 16) * STRIDE];

    const float4 *q0p = nullptr, *q1p = nullptr, *o0p, *o1p;
    const float4 *h0p = nullptr, *h1p = nullptr, *rc0p = nullptr, *rc1p = nullptr;
    if (USE_WS) {
        q0p = (const float4*)(qg + (size_t)b0 * DIM);
        q1p = (const float4*)(qg + (size_t)b1 * DIM);
        o0p = (const float4*)(og + (size_t)b0 * DIM);
        o1p = (const float4*)(og + (size_t)b1 * DIM);
    } else {
        int h0 = pairs[b0 * 2 + 0], r0 = pairs[b0 * 2 + 1];
        int h1 = pairs[b1 * 2 + 0], r1 = pairs[b1 * 2 + 1];
        h0p  = (const float4*)(ent  + (size_t)h0 * DIM);
        h1p  = (const float4*)(ent  + (size_t)h1 * DIM);
        rc0p = (const float4*)(relc + (size_t)r0 * DIM);
        rc1p = (const float4*)(relc + (size_t)r1 * DIM);
        o0p  = (const float4*)(relo + (size_t)r0 * DIM);
        o1p  = (const float4*)(relo + (size_t)r1 * DIM);
    }

    float am00 = 0.f, am01 = 0.f, am10 = 0.f, am11 = 0.f;  // sum max(d,o), [b][n]
    float ad00 = 0.f, ad01 = 0.f, ad10 = 0.f, ad11 = 0.f;  // sum d
    float ao0 = 0.f, ao1 = 0.f;                            // sum o (fallback path only)

#define ACC(cc, qq, oo, am, ad)            \
    {                                      \
        float d_ = fabsf((cc) - (qq));     \
        (am) += fmaxf(d_, (oo));           \
        (ad) += d_;                        \
    }

#pragma unroll 4
    for (int i = 0; i < D4; ++i) {
        float4 o0 = o0p[i], o1 = o1p[i];
        float4 q0, q1;
        if (USE_WS) {
            q0 = q0p[i];
            q1 = q1p[i];
        } else {
            float4 hv0 = h0p[i], cv0 = rc0p[i];
            float4 hv1 = h1p[i], cv1 = rc1p[i];
            q0 = make_float4(hv0.x + cv0.x, hv0.y + cv0.y, hv0.z + cv0.z, hv0.w + cv0.w);
            q1 = make_float4(hv1.x + cv1.x, hv1.y + cv1.y, hv1.z + cv1.z, hv1.w + cv1.w);
            ao0 += o0.x + o0.y + o0.z + o0.w;
            ao1 += o1.x + o1.y + o1.z + o1.w;
        }
        float4 c0 = c0p[i];
        float4 c1 = c1p[i];

        ACC(c0.x, q0.x, o0.x, am00, ad00) ACC(c0.y, q0.y, o0.y, am00, ad00)
        ACC(c0.z, q0.z, o0.z, am00, ad00) ACC(c0.w, q0.w, o0.w, am00, ad00)

        ACC(c1.x, q0.x, o0.x, am01, ad01) ACC(c1.y, q0.y, o0.y, am01, ad01)
        ACC(c1.z, q0.z, o0.z, am01, ad01) ACC(c1.w, q0.w, o0.w, am01, ad01)

        ACC(c0.x, q1.x, o1.x, am10, ad10) ACC(c0.y, q1.y, o1.y, am10, ad10)
        ACC(c0.z, q1.z, o1.z, am10, ad10) ACC(c0.w, q1.w, o1.w, am10, ad10)

        ACC(c1.x, q1.x, o1.x, am11, ad11) ACC(c1.y, q1.y, o1.y, am11, ad11)
        ACC(c1.z, q1.z, o1.z, am11, ad11) ACC(c1.w, q1.w, o1.w, am11, ad11)
    }
#undef ACC

    float base0, base1;
    if (USE_WS) {
        base0 = baseg[b0];
        base1 = baseg[b1];
    } else {
        float onec = onev[0];
        base0 = onec + 0.98f * ao0;
        base1 = onec + 0.98f * ao1;
    }

    const int gn0 = n_base + jn;
    const int gn1 = n_base + jn + 16;
    if (gn0 < NCAND) {
        out[(size_t)b0 * NCAND + gn0] = base0 - 0.98f * am00 - 0.02f * ad00;
        out[(size_t)b1 * NCAND + gn0] = base1 - 0.98f * am10 - 0.02f * ad10;
    }
    if (gn1 < NCAND) {
        out[(size_t)b0 * NCAND + gn1] = base0 - 0.98f * am01 - 0.02f * ad01;
        out[(size_t)b1 * NCAND + gn1] = base1 - 0.98f * am11 - 0.02f * ad11;
    }
}

extern "C" void kernel_launch(void* const* d_in, const int* in_sizes, int n_in,
                              void* d_out, int out_size, void* d_ws, size_t ws_size,
                              hipStream_t stream) {
    const float* ent   = (const float*)d_in[0];
    const float* relc  = (const float*)d_in[1];
    const float* relo  = (const float*)d_in[2];
    const float* onev  = (const float*)d_in[3];
    const int*   pairs = (const int*)d_in[4];
    const int*   cidx  = (const int*)d_in[5];   // row 0 of (4, NCAND)
    float*       out   = (float*)d_out;

    const int blocks = (NCAND + NT - 1) / NT;   // 454
    const size_t need = (size_t)(2 * B * DIM + B) * sizeof(float);

    if (ws_size >= need) {
        float* qg    = (float*)d_ws;
        float* og    = qg + (size_t)B * DIM;
        float* baseg = og + (size_t)B * DIM;
        prep_kernel<<<B, 64, 0, stream>>>(ent, relc, relo, onev, pairs, qg, og, baseg);
        box_score_kernel<true><<<blocks, THREADS, 0, stream>>>(
            ent, relc, relo, onev, pairs, cidx, qg, og, baseg, out);
    } else {
        box_score_kernel<false><<<blocks, THREADS, 0, stream>>>(
            ent, relc, relo, onev, pairs, cidx, nullptr, nullptr, nullptr, out);
    }
}